// Round 8
// baseline (52.104 us; speedup 1.0000x reference)
//
#include <hip/hip_runtime.h>
#include <hip/hip_bf16.h>

// RoIAlign forward, aligned=True, sampling_ratio=2, pooled 7x7, scale 0.25.
// (1) transpose x [B,C,H,W] f32 -> xt [B,H*W,C] bf16; one extra block in the
//     same kernel bitonic-sorts ROIs by (batch, y-center) -> perm.
// (2) roi_main: FOUR blocks per ROI (64-channel slices = one 128B cache line
//     per sample position). XCD mapping: slice = xcd&3, sorted-ROI half =
//     xcd>>2 -> per-XCD co-resident gather footprint ~1-2MB << 4MiB L2, so
//     the ~400MB logical corner stream is served from L2 not L3.
//     Lanes: cg=t&7 (8ch), xc=bit3 (x-corner pair), pslot=t>>4; x-corner
//     partials combined via shfl_xor(8). 12.5KB LDS out stage, contiguous
//     nontemporal write.

#define PH 7
#define PW 7
#define SCALE 0.25f
#define C_ 256
#define CS_ 64               // channels per slice (per block)
#define H_ 200
#define W_ 200
#define HW_ (H_ * W_)

typedef float f32x4 __attribute__((ext_vector_type(4)));

// -------- transpose + hidden ROI sort ---------------------------------------
__global__ void __launch_bounds__(512)
transpose_sort_kernel(const float* __restrict__ x, __hip_bfloat16* __restrict__ xt,
                      const float* __restrict__ rois, int K, int mode,
                      int* __restrict__ perm) {
    __shared__ float tile[64][65];
    __shared__ int s[1024];
    int bx = blockIdx.x;
    int tx = threadIdx.x;   // 0..63
    int ty = threadIdx.y;   // 0..7
    int t = ty * 64 + tx;   // 0..511

    if (bx == gridDim.x - 1) {
        if (blockIdx.y != 0 || blockIdx.z != 0) return;
        if (mode == 1) {
            for (int i = t; i < 1024; i += 512) {
                int key;
                if (i < K) {
                    const float* r = rois + (size_t)i * 5;
                    int b = (int)r[0];
                    float yc = (r[2] + r[4]) * (0.5f * SCALE);
                    int yq = min(max((int)yc, 0), 511);
                    key = ((b * 512 + yq) << 12) | i;
                } else {
                    key = 0x7FFFFFFF;
                }
                s[i] = key;
            }
            __syncthreads();
            for (int k2 = 2; k2 <= 1024; k2 <<= 1) {
                for (int j = k2 >> 1; j > 0; j >>= 1) {
                    int i = ((t & ~(j - 1)) << 1) | (t & (j - 1));
                    int l = i | j;
                    int a = s[i], b = s[l];
                    bool up = ((i & k2) == 0);
                    if ((a > b) == up) { s[i] = b; s[l] = a; }
                    __syncthreads();
                }
            }
            for (int i = t; i < K; i += 512) perm[i] = s[i] & 0xFFF;
        } else {
            for (int i = t; i < K; i += 512) perm[i] = i;
        }
        return;
    }

    int hw0 = bx * 64;
    int c0  = blockIdx.y * 64;
    int b   = blockIdx.z;
    const float* xb = x + (size_t)b * C_ * HW_;
#pragma unroll
    for (int j = 0; j < 8; ++j) {
        int cl = ty + 8 * j;
        tile[cl][tx] = __builtin_nontemporal_load(&xb[(size_t)(c0 + cl) * HW_ + hw0 + tx]);
    }
    __syncthreads();
    __hip_bfloat16* xtb = xt + (size_t)b * HW_ * C_;
#pragma unroll
    for (int j = 0; j < 8; ++j) {
        int rl = ty + 8 * j;
        float v = tile[tx][rl];
        xtb[(size_t)(hw0 + rl) * C_ + c0 + tx] = __float2bfloat16(v);
    }
}

// -------- main: 4 blocks (512 thr) per ROI, one per 64-ch slice --------------
__global__ void __launch_bounds__(512)
roi_main(const __hip_bfloat16* __restrict__ xt, const float* __restrict__ rois,
         const int* __restrict__ perm, float* __restrict__ out, int K, int mode) {
    __shared__ float s_out[CS_ * 49];         // 12544 B
    __shared__ int   s_ylo[14], s_yhi[14], s_xlo[14];
    __shared__ float s_wy0[14], s_wy1[14], s_wx0[14], s_wx1[14];
    __shared__ int   s_b;

    int k, slice;
    if (mode == 1) {
        // slice = xcd&3 (each XCD owns one 128B channel-line); half = xcd>>2
        int xcd  = blockIdx.x & 7;
        int pos  = blockIdx.x >> 3;           // 0 .. K/2-1
        slice    = xcd & 3;
        int rank = (xcd >> 2) * (K >> 1) + pos;
        k = perm[rank];
    } else {
        int nwg = gridDim.x;
        int q = nwg >> 3, rr = nwg & 7;
        int xcd = blockIdx.x & 7, pos = blockIdx.x >> 3;
        int logical = (xcd < rr ? xcd * (q + 1) : rr * (q + 1) + (xcd - rr) * q) + pos;
        k = perm[logical >> 2];
        slice = logical & 3;
    }

    int t = threadIdx.x;
    const float* r = rois + (size_t)k * 5;
    if (t == 0) s_b = (int)r[0];
    if (t < 28) {
        bool isy = t < 14;
        int i = isy ? t : t - 14;
        float start = (isy ? r[2] : r[1]) * SCALE - 0.5f;
        float end   = (isy ? r[4] : r[3]) * SCALE - 0.5f;
        float bin = (end - start) * (1.0f / 7.0f);
        int limit = isy ? H_ : W_;
        float pp   = (float)(i >> 1);
        float soff = (i & 1) ? 0.75f : 0.25f;
        float coord = fmaf(pp + soff, bin, start);
        float valid = (coord >= -1.0f && coord <= (float)limit) ? 1.0f : 0.0f;
        float cc = fmaxf(coord, 0.0f);
        int low0 = (int)floorf(cc);
        bool cap = low0 >= limit - 1;
        int lo = cap ? limit - 1 : low0;
        int hi = cap ? limit - 1 : low0 + 1;
        cc = cap ? (float)lo : cc;
        float l = cc - (float)lo;
        float w1 = l * valid, w0 = (1.0f - l) * valid;
        if (isy) {
            s_ylo[i] = lo; s_yhi[i] = hi;
            s_wy0[i] = w0 * 0.25f; s_wy1[i] = w1 * 0.25f;   // fold 1/4 average
        } else {
            s_xlo[i] = lo;
            s_wx0[i] = w0; s_wx1[i] = w1;
        }
    }
    __syncthreads();

    int cg    = t & 7;         // channels 8*cg..8*cg+7 within the slice
    int xc    = (t >> 3) & 1;  // x-corner
    int pslot = t >> 4;        // 0..31 -> p = pslot, pslot+32

    const __hip_bfloat16* xb = xt + (size_t)s_b * HW_ * C_ + slice * CS_ + cg * 8;

    for (int p = pslot; p < 49; p += 32) {
        int ph = p / 7;
        int pw = p - ph * 7;
        float acc[8];
#pragma unroll
        for (int j = 0; j < 8; ++j) acc[j] = 0.0f;

#pragma unroll
        for (int sy = 0; sy < 2; ++sy) {
            int ys = 2 * ph + sy;
            int yl = s_ylo[ys], yh = s_yhi[ys];
            float wy0 = s_wy0[ys], wy1 = s_wy1[ys];
#pragma unroll
            for (int sx = 0; sx < 2; ++sx) {
                int xs = 2 * pw + sx;
                int xi = s_xlo[xs] + xc;   // xc=1: xl+1 (=xh except cap, weight 0)
                float wxm = xc ? s_wx1[xs] : s_wx0[xs];
                float wl = wy0 * wxm, wh = wy1 * wxm;
                uint4 vlo = *(const uint4*)(xb + ((size_t)(yl * W_ + xi) << 8));
                uint4 vhi = *(const uint4*)(xb + ((size_t)(yh * W_ + xi) << 8));
                const unsigned* alo = (const unsigned*)&vlo;
                const unsigned* ahi = (const unsigned*)&vhi;
#pragma unroll
                for (int w = 0; w < 4; ++w) {
                    float flo0 = __uint_as_float(alo[w] << 16);
                    float flo1 = __uint_as_float(alo[w] & 0xffff0000u);
                    float fhi0 = __uint_as_float(ahi[w] << 16);
                    float fhi1 = __uint_as_float(ahi[w] & 0xffff0000u);
                    acc[2 * w]     = fmaf(wl, flo0, acc[2 * w]);
                    acc[2 * w]     = fmaf(wh, fhi0, acc[2 * w]);
                    acc[2 * w + 1] = fmaf(wl, flo1, acc[2 * w + 1]);
                    acc[2 * w + 1] = fmaf(wh, fhi1, acc[2 * w + 1]);
                }
            }
        }
#pragma unroll
        for (int j = 0; j < 8; ++j) {
            float v = acc[j] + __shfl_xor(acc[j], 8, 64);
            if (xc == 0) s_out[(cg * 8 + j) * 49 + p] = v;
        }
    }
    __syncthreads();

    // contiguous write: 12544 B = 784 f32x4
    const f32x4* sv = (const f32x4*)s_out;
    f32x4* ov = (f32x4*)(out + ((size_t)k * C_ + slice * CS_) * 49);
    for (int i = t; i < (CS_ * 49) / 4; i += 512)
        __builtin_nontemporal_store(sv[i], &ov[i]);
}

// -------- fallback (round-1 kernel) if ws too small -------------------------
__device__ __forceinline__ void axis_sample(float coord, int limit,
                                            int& lo, int& hi,
                                            float& w0, float& w1) {
    float fl = (float)limit;
    float valid = (coord >= -1.0f && coord <= fl) ? 1.0f : 0.0f;
    float c = fmaxf(coord, 0.0f);
    int low0 = (int)floorf(c);
    bool cap = low0 >= limit - 1;
    lo = cap ? limit - 1 : low0;
    hi = cap ? limit - 1 : low0 + 1;
    c = cap ? (float)lo : c;
    float l = c - (float)lo;
    w1 = l * valid;
    w0 = (1.0f - l) * valid;
}

__global__ void __launch_bounds__(256)
roi_align_fallback(const float* __restrict__ x, const float* __restrict__ rois,
                   float* __restrict__ out, int total) {
    int idx = blockIdx.x * blockDim.x + threadIdx.x;
    if (idx >= total) return;
    int pw = idx % PW;
    int ph = (idx / PW) % PH;
    int c  = (idx / (PW * PH)) % C_;
    int k  = idx / (PW * PH * C_);
    const float* r = rois + (size_t)k * 5;
    int b = (int)r[0];
    float start_w = r[1] * SCALE - 0.5f;
    float start_h = r[2] * SCALE - 0.5f;
    float bin_w = (r[3] * SCALE - 0.5f - start_w) / (float)PW;
    float bin_h = (r[4] * SCALE - 0.5f - start_h) / (float)PH;
    const float* xp = x + ((size_t)b * C_ + c) * (size_t)HW_;
    float acc = 0.0f;
#pragma unroll
    for (int sy = 0; sy < 2; ++sy) {
        float yc = start_h + ((float)ph + (sy + 0.5f) * 0.5f) * bin_h;
        int yl, yh; float wy0, wy1;
        axis_sample(yc, H_, yl, yh, wy0, wy1);
        const float* row0 = xp + (size_t)yl * W_;
        const float* row1 = xp + (size_t)yh * W_;
#pragma unroll
        for (int sx = 0; sx < 2; ++sx) {
            float xc2 = start_w + ((float)pw + (sx + 0.5f) * 0.5f) * bin_w;
            int xl, xh; float wx0, wx1;
            axis_sample(xc2, W_, xl, xh, wx0, wx1);
            acc += wy0 * (wx0 * row0[xl] + wx1 * row0[xh])
                 + wy1 * (wx0 * row1[xl] + wx1 * row1[xh]);
        }
    }
    out[idx] = acc * 0.25f;
}

extern "C" void kernel_launch(void* const* d_in, const int* in_sizes, int n_in,
                              void* d_out, int out_size, void* d_ws, size_t ws_size,
                              hipStream_t stream) {
    const float* x    = (const float*)d_in[0];
    const float* rois = (const float*)d_in[1];
    float* out = (float*)d_out;
    int K = in_sizes[1] / 5;

    size_t xtbytes = (size_t)2 * HW_ * C_ * sizeof(__hip_bfloat16);  // 40.96 MB
    size_t need = xtbytes + 4096 * sizeof(int);
    if (ws_size >= need && K <= 4096 && K >= 8) {
        __hip_bfloat16* xt = (__hip_bfloat16*)d_ws;
        int* perm = (int*)((char*)d_ws + xtbytes);
        int mode = (K % 8 == 0 && K <= 1024) ? 1 : 0;
        dim3 tgrid(HW_ / 64 + 1, C_ / 64, 2);   // +1: sort block
        dim3 tblock(64, 8);
        transpose_sort_kernel<<<tgrid, tblock, 0, stream>>>(x, xt, rois, K, mode, perm);
        roi_main<<<K * 4, 512, 0, stream>>>(xt, rois, perm, out, K, mode);
    } else {
        int total = K * C_ * PH * PW;
        roi_align_fallback<<<(total + 255) / 256, 256, 0, stream>>>(x, rois, out, total);
    }
}